// Round 5
// baseline (2793.743 us; speedup 1.0000x reference)
//
#include <hip/hip_runtime.h>
#include <float.h>

#define NS 1536
#define DD 64

// ws layout (float elements)
static const size_t OFF_A  = 0;                          // A = h_sat + b1: [1536][64]
static const size_t OFF_C2 = 98304;                      // C2 = h_uav transposed [16][1536][4]
static const size_t OFF_L  = 196608;                     // logits [1536][1536]
static const size_t OFF_AS = 196608 + (size_t)NS * NS;   // int assign [1536]
// top_idx (ushort, 1536*256 = 786432 B) ALIASES the A/C2 region (dead after kB).

// ---------------- Kernel A: first-layer projections ----------------
__global__ __launch_bounds__(64) void kA(const float* __restrict__ sat,
                                         const float* __restrict__ uav,
                                         const float* __restrict__ W1,
                                         const float* __restrict__ b1,
                                         float* __restrict__ A,
                                         float* __restrict__ C2) {
    const int row = blockIdx.x;
    const int d = threadIdx.x;
    float accA = b1[d];
    float accC = 0.f;
    const float* __restrict__ satr = sat + row * DD;
    const float* __restrict__ uavr = uav + row * DD;
#pragma unroll 8
    for (int k = 0; k < DD; ++k) {
        accA = fmaf(satr[k], W1[k * DD + d], accA);
        accC = fmaf(uavr[k], W1[(DD + k) * DD + d], accC);
    }
    A[row * DD + d] = accA;
    C2[((size_t)(d >> 2) * NS + row) * 4 + (d & 3)] = accC;
}

// ---------------- Kernel B: all-pairs logits ----------------
__global__ __launch_bounds__(256) void kB(const float* __restrict__ A,
                                          const float* __restrict__ C2,
                                          const float* __restrict__ W2,
                                          const float* __restrict__ b2,
                                          const float* __restrict__ W3,
                                          float* __restrict__ L) {
    const int lane = threadIdx.x & 63;
    const int wave = threadIdx.x >> 6;
    const int i = __builtin_amdgcn_readfirstlane(blockIdx.x * 4 + wave);
    const int jbase = blockIdx.y * 256;
    const float* __restrict__ Ar = A + (size_t)i * DD;

    float u[4][32];
#pragma unroll
    for (int o = 0; o < 32; ++o) {
        const float b = b2[o];
        u[0][o] = b; u[1][o] = b; u[2][o] = b; u[3][o] = b;
    }

    const float4* __restrict__ C2v = (const float4*)C2;

    for (int d4 = 0; d4 < 16; ++d4) {
        float c[4][4];
#pragma unroll
        for (int p = 0; p < 4; ++p) {
            const float4 t = C2v[(size_t)d4 * NS + jbase + p * 64 + lane];
            c[p][0] = t.x; c[p][1] = t.y; c[p][2] = t.z; c[p][3] = t.w;
        }
#pragma unroll
        for (int dd = 0; dd < 4; ++dd) {
            const float a = Ar[d4 * 4 + dd];
            const float v0 = fmaxf(a + c[0][dd], 0.f);
            const float v1 = fmaxf(a + c[1][dd], 0.f);
            const float v2 = fmaxf(a + c[2][dd], 0.f);
            const float v3 = fmaxf(a + c[3][dd], 0.f);
            const float* __restrict__ w2r = W2 + (d4 * 4 + dd) * 32;
#pragma unroll
            for (int o = 0; o < 32; ++o) {
                const float w = w2r[o];
                u[0][o] = fmaf(v0, w, u[0][o]);
                u[1][o] = fmaf(v1, w, u[1][o]);
                u[2][o] = fmaf(v2, w, u[2][o]);
                u[3][o] = fmaf(v3, w, u[3][o]);
            }
        }
    }

#pragma unroll
    for (int p = 0; p < 4; ++p) {
        float acc = 0.f;
#pragma unroll
        for (int o = 0; o < 32; ++o)
            acc = fmaf(fmaxf(u[p][o], 0.f), W3[o], acc);
        L[(size_t)i * NS + jbase + p * 64 + lane] = acc;
    }
}

// ---------------- Kernel C: per-row sorted top-256 via 16-bit radix ----------------
// Output: top[row*256 + rank] = col (ushort), rank-major, sorted val desc / col asc.
__global__ __launch_bounds__(256) void kC(const float* __restrict__ L,
                                          unsigned short* __restrict__ top) {
    __shared__ int hist[256];
    __shared__ int suff[256];
    __shared__ float cv[1024];
    __shared__ int ci[1024];
    __shared__ int s_cnt, s_B0, s_base, s_B1;
    const int t = threadIdx.x;
    const int row = blockIdx.x;
    const float* __restrict__ Lr = L + (size_t)row * NS;

    top[row * 256 + t] = 0xFFFFu;   // sentinel (degenerate rows -> kD fallback)

    hist[t] = 0;
    if (t == 0) s_cnt = 0;
    __syncthreads();

    unsigned ub[6]; float fv[6];
#pragma unroll
    for (int k = 0; k < 6; ++k) {
        const float x = Lr[t + 256 * k];
        fv[k] = x;
        unsigned b = __float_as_uint(x);
        b = (b & 0x80000000u) ? ~b : (b | 0x80000000u);
        ub[k] = b;
        atomicAdd(&hist[b >> 24], 1);
    }
    __syncthreads();

    suff[t] = hist[t];
    __syncthreads();
    for (int off = 1; off < 256; off <<= 1) {
        const int v = (t + off < 256) ? suff[t + off] : 0;
        __syncthreads();
        suff[t] += v;
        __syncthreads();
    }
    if (suff[t] >= 256 && (t == 255 || suff[t + 1] < 256)) {
        s_B0 = t;
        s_base = (t == 255) ? 0 : suff[t + 1];
    }
    __syncthreads();
    const unsigned B0 = (unsigned)s_B0;
    const int base = s_base;

    hist[t] = 0;
    __syncthreads();
#pragma unroll
    for (int k = 0; k < 6; ++k)
        if ((ub[k] >> 24) == B0) atomicAdd(&hist[(ub[k] >> 16) & 255], 1);
    __syncthreads();
    suff[t] = hist[t];
    __syncthreads();
    for (int off = 1; off < 256; off <<= 1) {
        const int v = (t + off < 256) ? suff[t + off] : 0;
        __syncthreads();
        suff[t] += v;
        __syncthreads();
    }
    const int need = 256 - base;
    if (suff[t] >= need && (t == 255 || suff[t + 1] < need)) s_B1 = t;
    __syncthreads();
    const unsigned B1 = (unsigned)s_B1;
    const int m = base + suff[B1];
    if (m > 1024) return;

#pragma unroll
    for (int k = 0; k < 6; ++k) {
        const unsigned hi = ub[k] >> 24;
        const unsigned mid = (ub[k] >> 16) & 255u;
        if (hi > B0 || (hi == B0 && mid >= B1)) {
            const int pos = atomicAdd(&s_cnt, 1);
            cv[pos] = fv[k];
            ci[pos] = t + 256 * k;
        }
    }
    __syncthreads();

    for (int e = t; e < m; e += 256) {
        const float v = cv[e]; const int id = ci[e];
        int r = 0;
        for (int s2 = 0; s2 < m; ++s2) {
            const float vs = cv[s2];
            if (vs > v || (vs == v && ci[s2] < id)) ++r;
        }
        if (r < 256) top[row * 256 + r] = (unsigned short)id;
    }
}

// ---------------- Kernel D: parallel Gale-Shapley auction ----------------
// Serial greedy == serial dictatorship by row index == row-proposing deferred
// acceptance when every column prefers the lowest row (classical equivalence).
// holder[col] = lowest row ever proposing (atomicMin, monotone decreasing).
// Each of 768 threads owns rows tid and tid+768; proposes down its sorted
// top-256 list (register-buffered 8 at a time); rows exhausting the list do a
// wave-cooperative masked argmax over mask (holder[c] > row), which exactly
// equals the not-yet-rejected column set. Races are benign: stale-high holder
// reads cause a lost proposal and a retry next round.
__global__ __launch_bounds__(768) void kD(const float* __restrict__ L,
                                          const unsigned short* __restrict__ top,
                                          int* __restrict__ assign) {
    __shared__ int holder[NS];
    const int tid = threadIdx.x;
    const int lane = tid & 63;
    for (int k = tid; k < NS; k += 768) holder[k] = 0x7FFFFFFF;
    __syncthreads();

    const int row0 = tid, row1 = tid + 768;
    int ptr0 = 0, ptr1 = 0;
    int pb0 = -8, pb1 = -8;
    uint4 buf0 = {0, 0, 0, 0}, buf1 = {0, 0, 0, 0};
    int myc0 = -1, myc1 = -1;
    bool act0 = true, act1 = true;

    for (int round = 0; round < 5000; ++round) {
        bool fb0 = false, fb1 = false;

        if (act0) {
            int c = -1;
            while (ptr0 < 256) {
                if (ptr0 - pb0 >= 8) {
                    const int nb = ptr0 & ~7;
                    buf0 = *(const uint4*)(top + ((size_t)row0 << 8) + nb);
                    pb0 = nb;
                }
                const int k = ptr0 - pb0;
                unsigned w = (k < 2) ? buf0.x : (k < 4) ? buf0.y
                           : (k < 6) ? buf0.z : buf0.w;
                w = (k & 1) ? (w >> 16) : (w & 0xFFFFu);
                if (w >= NS) { ptr0 = 256; break; }
                if (holder[w] > row0) { c = (int)w; break; }
                ++ptr0;
            }
            if (c >= 0) { atomicMin(&holder[c], row0); myc0 = c; }
            else fb0 = true;
        }
        if (act1) {
            int c = -1;
            while (ptr1 < 256) {
                if (ptr1 - pb1 >= 8) {
                    const int nb = ptr1 & ~7;
                    buf1 = *(const uint4*)(top + ((size_t)row1 << 8) + nb);
                    pb1 = nb;
                }
                const int k = ptr1 - pb1;
                unsigned w = (k < 2) ? buf1.x : (k < 4) ? buf1.y
                           : (k < 6) ? buf1.z : buf1.w;
                w = (k & 1) ? (w >> 16) : (w & 0xFFFFu);
                if (w >= NS) { ptr1 = 256; break; }
                if (holder[w] > row1) { c = (int)w; break; }
                ++ptr1;
            }
            if (c >= 0) { atomicMin(&holder[c], row1); myc1 = c; }
            else fb1 = true;
        }

        // wave-cooperative fallback: masked argmax over (holder[col] > row)
#pragma unroll
        for (int slot = 0; slot < 2; ++slot) {
            unsigned long long m = __ballot(slot == 0 ? fb0 : fb1);
            while (m) {
                const int l = __ffsll(m) - 1;
                m &= m - 1;
                const int rr = (tid - lane) + l + (slot ? 768 : 0);
                const float* __restrict__ Lr = L + (size_t)rr * NS;
                float bv = -FLT_MAX; int bi = NS;
#pragma unroll
                for (int k = 0; k < 24; ++k) {
                    const int col = lane + (k << 6);
                    const float v = Lr[col];
                    if (holder[col] > rr &&
                        (v > bv || (v == bv && col < bi))) { bv = v; bi = col; }
                }
#pragma unroll
                for (int o = 32; o >= 1; o >>= 1) {
                    const float ov = __shfl_xor(bv, o);
                    const int oi = __shfl_xor(bi, o);
                    if (ov > bv || (ov == bv && oi < bi)) { bv = ov; bi = oi; }
                }
                if (lane == l && bi < NS) {
                    atomicMin(&holder[bi], rr);
                    if (slot == 0) myc0 = bi; else myc1 = bi;
                }
            }
        }

        __syncthreads();   // all proposals visible
        act0 = !(myc0 >= 0 && holder[myc0] == row0);
        act1 = !(myc1 >= 0 && holder[myc1] == row1);
        if (__syncthreads_count((int)(act0 || act1)) == 0) break;
    }

    assign[row0] = myc0;
    assign[row1] = myc1;
}

// ---------------- Kernel E: emit [1536][2][64] output ----------------
__global__ __launch_bounds__(128) void kE(const float* __restrict__ sat,
                                          const float* __restrict__ uav,
                                          const int* __restrict__ assign,
                                          float* __restrict__ out) {
    const int i = blockIdx.x;
    const int t = threadIdx.x;
    if (t < 64) out[(size_t)i * 128 + t] = sat[(size_t)i * DD + t];
    else        out[(size_t)i * 128 + t] = uav[(size_t)assign[i] * DD + (t - 64)];
}

extern "C" void kernel_launch(void* const* d_in, const int* in_sizes, int n_in,
                              void* d_out, int out_size, void* d_ws, size_t ws_size,
                              hipStream_t stream) {
    const float* sat = (const float*)d_in[0];
    const float* uav = (const float*)d_in[1];
    const float* W1  = (const float*)d_in[2];
    const float* b1  = (const float*)d_in[3];
    const float* W2  = (const float*)d_in[4];
    const float* b2  = (const float*)d_in[5];
    const float* W3  = (const float*)d_in[6];
    // d_in[7] = b3: sigmoid(x+b3) monotone in x — argmax unchanged.

    float* ws = (float*)d_ws;
    float* A   = ws + OFF_A;
    float* C2  = ws + OFF_C2;
    float* L   = ws + OFF_L;
    int* assign = (int*)(ws + OFF_AS);
    unsigned short* top = (unsigned short*)(ws + OFF_A);  // aliases A/C2 (dead after kB)

    hipLaunchKernelGGL(kA, dim3(NS), dim3(64), 0, stream, sat, uav, W1, b1, A, C2);
    hipLaunchKernelGGL(kB, dim3(NS / 4, NS / 256), dim3(256), 0, stream,
                       A, C2, W2, b2, W3, L);
    hipLaunchKernelGGL(kC, dim3(NS), dim3(256), 0, stream, L, top);
    hipLaunchKernelGGL(kD, dim3(1), dim3(768), 0, stream, L, top, assign);
    hipLaunchKernelGGL(kE, dim3(NS), dim3(128), 0, stream, sat, uav, assign,
                       (float*)d_out);
}